// Round 8
// baseline (955.648 us; speedup 1.0000x reference)
//
#include <hip/hip_runtime.h>
#include <hip/hip_bf16.h>
#include <math.h>

typedef __bf16 bf16_t;
typedef __bf16 bf16x4 __attribute__((ext_vector_type(4)));
typedef __bf16 bf16x8 __attribute__((ext_vector_type(8)));
typedef float  f32x4  __attribute__((ext_vector_type(4)));
typedef float  f32x16 __attribute__((ext_vector_type(16)));

#define DIN   3072
#define NOUT  24576
#define HALF  12288
#define MTOK  4096
#define BK    64

#define GLD16(gp, lp) \
    __builtin_amdgcn_global_load_lds((const __attribute__((address_space(1))) void*)(gp), \
                                     (__attribute__((address_space(3))) void*)(lp), 16, 0, 0)

// ---------------- K1: per-token activation int4 fake-quant -> bf16 ----------------
__global__ __launch_bounds__(256) void k_quant_x(const float* __restrict__ x,
                                                 bf16_t* __restrict__ xq) {
    int m = blockIdx.x;
    int t = threadIdx.x;
    const float4* row = reinterpret_cast<const float4*>(x + (size_t)m * DIN);
    float4 v[3];
    float vm = 0.f;
#pragma unroll
    for (int i = 0; i < 3; ++i) {
        v[i] = row[t + i * 256];
        vm = fmaxf(vm, fmaxf(fmaxf(fabsf(v[i].x), fabsf(v[i].y)),
                             fmaxf(fabsf(v[i].z), fabsf(v[i].w))));
    }
#pragma unroll
    for (int d = 1; d < 64; d <<= 1) vm = fmaxf(vm, __shfl_xor(vm, d));
    __shared__ float sm[4];
    if ((t & 63) == 0) sm[t >> 6] = vm;
    __syncthreads();
    vm = fmaxf(fmaxf(sm[0], sm[1]), fmaxf(sm[2], sm[3]));
    float s = fmaxf(vm * (1.f / 7.f), 1e-8f);
    float inv = 1.f / s;
    bf16x4* orow = reinterpret_cast<bf16x4*>(xq + (size_t)m * DIN);
#pragma unroll
    for (int i = 0; i < 3; ++i) {
        bf16x4 o;
        o[0] = (bf16_t)(fminf(fmaxf(rintf(v[i].x * inv), -8.f), 7.f) * s);
        o[1] = (bf16_t)(fminf(fmaxf(rintf(v[i].y * inv), -8.f), 7.f) * s);
        o[2] = (bf16_t)(fminf(fmaxf(rintf(v[i].z * inv), -8.f), 7.f) * s);
        o[3] = (bf16_t)(fminf(fmaxf(rintf(v[i].w * inv), -8.f), 7.f) * s);
        orow[t + i * 256] = o;
    }
}

// ---------------- K2: per-(row, group-of-64) weight int4 fake-quant -> bf16 -------
__global__ __launch_bounds__(256) void k_quant_w(const float* __restrict__ w,
                                                 bf16_t* __restrict__ wq) {
    size_t idx = (size_t)blockIdx.x * 256 + threadIdx.x;  // float4 index
    float4 v = reinterpret_cast<const float4*>(w)[idx];
    float vm = fmaxf(fmaxf(fabsf(v.x), fabsf(v.y)), fmaxf(fabsf(v.z), fabsf(v.w)));
    vm = fmaxf(vm, __shfl_xor(vm, 1));
    vm = fmaxf(vm, __shfl_xor(vm, 2));
    vm = fmaxf(vm, __shfl_xor(vm, 4));
    vm = fmaxf(vm, __shfl_xor(vm, 8));
    float s = fmaxf(vm * (1.f / 7.f), 1e-8f);
    float inv = 1.f / s;
    bf16x4 o;
    o[0] = (bf16_t)(fminf(fmaxf(rintf(v.x * inv), -8.f), 7.f) * s);
    o[1] = (bf16_t)(fminf(fmaxf(rintf(v.y * inv), -8.f), 7.f) * s);
    o[2] = (bf16_t)(fminf(fmaxf(rintf(v.z * inv), -8.f), 7.f) * s);
    o[3] = (bf16_t)(fminf(fmaxf(rintf(v.w * inv), -8.f), 7.f) * s);
    reinterpret_cast<bf16x4*>(wq)[idx] = o;
}

// ---------------- K3: T = x @ lora_down^T  (full-precision x), bf16 out -----------
__global__ __launch_bounds__(256) void k_lora_t(const float* __restrict__ x,
                                                const float* __restrict__ ld,
                                                bf16_t* __restrict__ T) {
    int r = threadIdx.x & 31;
    int m = blockIdx.x * 8 + (threadIdx.x >> 5);
    const float4* xr = reinterpret_cast<const float4*>(x + (size_t)m * DIN);
    const float4* lr = reinterpret_cast<const float4*>(ld + (size_t)r * DIN);
    float acc = 0.f;
#pragma unroll 4
    for (int i = 0; i < DIN / 4; ++i) {
        float4 a = xr[i], b = lr[i];
        acc += a.x * b.x + a.y * b.y + a.z * b.z + a.w * b.w;
    }
    T[(size_t)m * 32 + r] = (bf16_t)acc;
}

// ---------------- K3b: cast lora_up f32 -> bf16 -----------------------------------
__global__ __launch_bounds__(256) void k_cvt_lu(const float* __restrict__ lu,
                                                bf16_t* __restrict__ lub) {
    size_t idx = (size_t)blockIdx.x * 256 + threadIdx.x;  // float4 index
    float4 v = reinterpret_cast<const float4*>(lu)[idx];
    bf16x4 o;
    o[0] = (bf16_t)v.x; o[1] = (bf16_t)v.y; o[2] = (bf16_t)v.z; o[3] = (bf16_t)v.w;
    reinterpret_cast<bf16x4*>(lub)[idx] = o;
}

// ---------------- K4: fused GEMM, 32x32x16 MFMA on round-3 structure --------------
// 512 thr = 8 waves. Waves 0-3: H tile (2x2 of 64x64); waves 4-7: G tile.
// Per wave: 2x2 frags of 32x32, acc = 4 x f32x16. 16 MFMA / K-tile / wave.
// Both-sides XOR swizzle (global source chunk col ^= row&7; ds_read col16 ^= row&7).
// Frag layout (m74/m101): A/B row|col = lane&31, k = (lane>>5)*8+e;
//                         C/D col = lane&31, row = (r&3)+8*(r>>2)+4*(lane>>5).
__global__ __launch_bounds__(512, 4) void k_gemm(const bf16_t* __restrict__ xq,
                                                 const bf16_t* __restrict__ wq,
                                                 const bf16_t* __restrict__ T,
                                                 const bf16_t* __restrict__ lub,
                                                 float* __restrict__ out) {
    __shared__ __align__(16) char smem[65536];       // staging 48KB; epilogue exch 64KB
    bf16_t* sA = (bf16_t*)smem;                      // [128][64]
    bf16_t* sH = sA + 128 * BK;
    bf16_t* sG = sH + 128 * BK;

    const int tid = threadIdx.x, lane = tid & 63, w = tid >> 6;
    const int half = w >> 2;                 // 0 = H, 1 = G
    const int wr = (w >> 1) & 1, wc = w & 1;
    const int l31 = lane & 31, lh = lane >> 5;

    // XCD-bijective swizzle (3072 % 8 == 0)
    const int nwg = gridDim.x;
    const int cpx = nwg >> 3;
    const int swz = ((int)blockIdx.x & 7) * cpx + ((int)blockIdx.x >> 3);
    const int mt = swz & 31, nt = swz >> 5;  // mt fast: neighbors share B tiles
    const int m0 = mt * 128, c0 = nt * 128;

    f32x16 acc[2][2];
#pragma unroll
    for (int i = 0; i < 2; ++i)
#pragma unroll
        for (int j = 0; j < 2; ++j)
#pragma unroll
            for (int r = 0; r < 16; ++r) acc[i][j][r] = 0.f;

    const char* sAb = (const char*)sA;
    const char* sBb = (const char*)(half ? sG : sH);

    for (int k0 = 0; k0 < DIN; k0 += BK) {
        __syncthreads();
        // stage 3 tiles of 128x64 bf16; 1024 16B-chunks each; 512 lanes -> 2 rounds.
        // source col pre-swizzled: gc16 = (chunk&7) ^ (row&7); LDS dest linear.
#pragma unroll
        for (int r = 0; r < 2; ++r) {
            int chunk = r * 512 + tid;
            int row = chunk >> 3;
            int gc = ((chunk & 7) ^ (row & 7)) * 8;
            int ldsoff = r * 4096 + w * 512;
            GLD16(xq + (size_t)(m0 + row) * DIN + k0 + gc, sA + ldsoff);
            GLD16(wq + (size_t)(c0 + row) * DIN + k0 + gc, sH + ldsoff);
            GLD16(wq + (size_t)(c0 + HALF + row) * DIN + k0 + gc, sG + ldsoff);
        }
        __syncthreads();   // vmcnt(0) drain before barrier (compiler-emitted)

#pragma unroll
        for (int ks = 0; ks < 4; ++ks) {
            int c16 = ks * 2 + lh;           // 16B-column of this k-slice
            bf16x8 a[2], b[2];
#pragma unroll
            for (int mi = 0; mi < 2; ++mi) {
                int ra = wr * 64 + mi * 32 + l31;
                a[mi] = *reinterpret_cast<const bf16x8*>(sAb + ra * 128 + ((c16 ^ (ra & 7)) << 4));
            }
#pragma unroll
            for (int ni = 0; ni < 2; ++ni) {
                int rb = wc * 64 + ni * 32 + l31;
                b[ni] = *reinterpret_cast<const bf16x8*>(sBb + rb * 128 + ((c16 ^ (rb & 7)) << 4));
            }
#pragma unroll
            for (int mi = 0; mi < 2; ++mi)
#pragma unroll
                for (int ni = 0; ni < 2; ++ni)
                    acc[mi][ni] = __builtin_amdgcn_mfma_f32_32x32x16_bf16(a[mi], b[ni], acc[mi][ni], 0, 0, 0);
        }
    }

    // ---- LoRA correction: RANK=32 = two K=16 MFMA steps per fragment ----
#pragma unroll
    for (int ks2 = 0; ks2 < 2; ++ks2) {
        bf16x8 tf[2], lu[2];
#pragma unroll
        for (int mi = 0; mi < 2; ++mi) {
            int row = m0 + wr * 64 + mi * 32 + l31;
            tf[mi] = *reinterpret_cast<const bf16x8*>(T + (size_t)row * 32 + ks2 * 16 + lh * 8);
        }
#pragma unroll
        for (int ni = 0; ni < 2; ++ni) {
            int ocol = c0 + half * HALF + wc * 64 + ni * 32 + l31;
            lu[ni] = *reinterpret_cast<const bf16x8*>(lub + (size_t)ocol * 32 + ks2 * 16 + lh * 8);
        }
#pragma unroll
        for (int mi = 0; mi < 2; ++mi)
#pragma unroll
            for (int ni = 0; ni < 2; ++ni)
                acc[mi][ni] = __builtin_amdgcn_mfma_f32_32x32x16_bf16(tf[mi], lu[ni], acc[mi][ni], 0, 0, 0);
    }

    // ---- GEGLU epilogue via LDS exchange: G waves write gelu(g); H waves combine --
    // C/D layout: col = lane&31, row = (r&3) + 8*(r>>2) + 4*lh.
    // exch write/read: lanes 0-31 same row, cols consecutive; high half row+4 ->
    // same banks 2-way (free, m136). No extra swizzle needed.
    __syncthreads();                    // all LDS staging reads done; reuse smem
    float* exch = (float*)smem;         // [128][128] f32
    if (half) {
#pragma unroll
        for (int mi = 0; mi < 2; ++mi)
#pragma unroll
            for (int ni = 0; ni < 2; ++ni) {
                int col = wc * 64 + ni * 32 + l31;
#pragma unroll
                for (int r = 0; r < 16; ++r) {
                    int row = wr * 64 + mi * 32 + (r & 3) + 8 * (r >> 2) + 4 * lh;
                    float g = acc[mi][ni][r];
                    float gl = 0.5f * g * (1.0f + erff(g * 0.70710678118654752f));
                    exch[row * 128 + col] = gl;
                }
            }
    }
    __syncthreads();
    if (!half) {
#pragma unroll
        for (int mi = 0; mi < 2; ++mi)
#pragma unroll
            for (int ni = 0; ni < 2; ++ni) {
                int col = wc * 64 + ni * 32 + l31;
#pragma unroll
                for (int r = 0; r < 16; ++r) {
                    int row = wr * 64 + mi * 32 + (r & 3) + 8 * (r >> 2) + 4 * lh;
                    float gl = exch[row * 128 + col];
                    out[(size_t)(m0 + row) * HALF + c0 + col] = acc[mi][ni][r] * gl;
                }
            }
    }
}

extern "C" void kernel_launch(void* const* d_in, const int* in_sizes, int n_in,
                              void* d_out, int out_size, void* d_ws, size_t ws_size,
                              hipStream_t stream) {
    const float* x  = (const float*)d_in[0];   // [1,4096,3072]
    const float* wr = (const float*)d_in[1];   // [24576,3072]
    const float* ld = (const float*)d_in[2];   // [32,3072]
    const float* lu = (const float*)d_in[3];   // [24576,32]
    float* out = (float*)d_out;                // [4096,12288] f32

    bf16_t* xq  = (bf16_t*)d_ws;
    bf16_t* wq  = xq + (size_t)MTOK * DIN;
    bf16_t* T   = wq + (size_t)NOUT * DIN;
    bf16_t* lub = T  + (size_t)MTOK * 32;

    k_quant_x<<<MTOK, 256, 0, stream>>>(x, xq);
    k_quant_w<<<(NOUT * (DIN / 4)) / 256, 256, 0, stream>>>(wr, wq);
    k_lora_t<<<MTOK / 8, 256, 0, stream>>>(x, ld, T);
    k_cvt_lu<<<(NOUT * 32 / 4) / 256, 256, 0, stream>>>(lu, lub);
    k_gemm<<<(MTOK / 128) * (HALF / 128), 512, 0, stream>>>(xq, wq, T, lub, out);
}

// Round 9
// 848.440 us; speedup vs baseline: 1.1264x; 1.1264x over previous
//
#include <hip/hip_runtime.h>
#include <hip/hip_bf16.h>
#include <math.h>

typedef __bf16 bf16_t;
typedef __bf16 bf16x4 __attribute__((ext_vector_type(4)));
typedef __bf16 bf16x8 __attribute__((ext_vector_type(8)));
typedef float  f32x4  __attribute__((ext_vector_type(4)));

#define DIN   3072
#define NOUT  24576
#define HALF  12288
#define MTOK  4096
#define BM    128
#define BN    128
#define BK    64

// fused-prepass block ranges (small kernels first: overlap under quant_w's body)
#define NB_LORA  (MTOK / 8)                       // 512
#define NB_QX    (MTOK)                           // 4096
#define NB_CVT   (NOUT * 32 / 4 / 256)            // 768
#define NB_QW    (NOUT * (DIN / 4) / 256)         // 73728
#define B0       (NB_LORA)
#define B1       (B0 + NB_QX)
#define B2       (B1 + NB_CVT)
#define NB_PREP  (B2 + NB_QW)

#define GLD16(gp, lp) \
    __builtin_amdgcn_global_load_lds((const __attribute__((address_space(1))) void*)(gp), \
                                     (__attribute__((address_space(3))) void*)(lp), 16, 0, 0)

// ---------------- fused prepass: lora_t | quant_x | cvt_lu | quant_w --------------
__global__ __launch_bounds__(256) void k_prep(const float* __restrict__ x,
                                              const float* __restrict__ w,
                                              const float* __restrict__ ld,
                                              const float* __restrict__ lu,
                                              bf16_t* __restrict__ xq,
                                              bf16_t* __restrict__ wq,
                                              bf16_t* __restrict__ T,
                                              bf16_t* __restrict__ lub) {
    const int bid = blockIdx.x;
    const int t = threadIdx.x;

    if (bid < B0) {
        // ---- T = x @ lora_down^T (full-precision x), 8 tokens x 32 ranks ----
        int r = t & 31;
        int m = bid * 8 + (t >> 5);
        const float4* xr = reinterpret_cast<const float4*>(x + (size_t)m * DIN);
        const float4* lr = reinterpret_cast<const float4*>(ld + (size_t)r * DIN);
        float acc = 0.f;
#pragma unroll 4
        for (int i = 0; i < DIN / 4; ++i) {
            float4 a = xr[i], b = lr[i];
            acc += a.x * b.x + a.y * b.y + a.z * b.z + a.w * b.w;
        }
        T[(size_t)m * 32 + r] = (bf16_t)acc;
    } else if (bid < B1) {
        // ---- per-token activation int4 fake-quant -> bf16 ----
        int m = bid - B0;
        const float4* row = reinterpret_cast<const float4*>(x + (size_t)m * DIN);
        float4 v[3];
        float vm = 0.f;
#pragma unroll
        for (int i = 0; i < 3; ++i) {
            v[i] = row[t + i * 256];
            vm = fmaxf(vm, fmaxf(fmaxf(fabsf(v[i].x), fabsf(v[i].y)),
                                 fmaxf(fabsf(v[i].z), fabsf(v[i].w))));
        }
#pragma unroll
        for (int d = 1; d < 64; d <<= 1) vm = fmaxf(vm, __shfl_xor(vm, d));
        __shared__ float sm[4];
        if ((t & 63) == 0) sm[t >> 6] = vm;
        __syncthreads();
        vm = fmaxf(fmaxf(sm[0], sm[1]), fmaxf(sm[2], sm[3]));
        float s = fmaxf(vm * (1.f / 7.f), 1e-8f);
        float inv = 1.f / s;
        bf16x4* orow = reinterpret_cast<bf16x4*>(xq + (size_t)m * DIN);
#pragma unroll
        for (int i = 0; i < 3; ++i) {
            bf16x4 o;
            o[0] = (bf16_t)(fminf(fmaxf(rintf(v[i].x * inv), -8.f), 7.f) * s);
            o[1] = (bf16_t)(fminf(fmaxf(rintf(v[i].y * inv), -8.f), 7.f) * s);
            o[2] = (bf16_t)(fminf(fmaxf(rintf(v[i].z * inv), -8.f), 7.f) * s);
            o[3] = (bf16_t)(fminf(fmaxf(rintf(v[i].w * inv), -8.f), 7.f) * s);
            orow[t + i * 256] = o;
        }
    } else if (bid < B2) {
        // ---- cast lora_up f32 -> bf16 ----
        size_t idx = (size_t)(bid - B1) * 256 + t;
        float4 v = reinterpret_cast<const float4*>(lu)[idx];
        bf16x4 o;
        o[0] = (bf16_t)v.x; o[1] = (bf16_t)v.y; o[2] = (bf16_t)v.z; o[3] = (bf16_t)v.w;
        reinterpret_cast<bf16x4*>(lub)[idx] = o;
    } else {
        // ---- per-(row, group-of-64) weight int4 fake-quant -> bf16 ----
        size_t idx = (size_t)(bid - B2) * 256 + t;   // float4 index
        float4 v = reinterpret_cast<const float4*>(w)[idx];
        float vm = fmaxf(fmaxf(fabsf(v.x), fabsf(v.y)), fmaxf(fabsf(v.z), fabsf(v.w)));
        vm = fmaxf(vm, __shfl_xor(vm, 1));
        vm = fmaxf(vm, __shfl_xor(vm, 2));
        vm = fmaxf(vm, __shfl_xor(vm, 4));
        vm = fmaxf(vm, __shfl_xor(vm, 8));
        float s = fmaxf(vm * (1.f / 7.f), 1e-8f);
        float inv = 1.f / s;
        bf16x4 o;
        o[0] = (bf16_t)(fminf(fmaxf(rintf(v.x * inv), -8.f), 7.f) * s);
        o[1] = (bf16_t)(fminf(fmaxf(rintf(v.y * inv), -8.f), 7.f) * s);
        o[2] = (bf16_t)(fminf(fmaxf(rintf(v.z * inv), -8.f), 7.f) * s);
        o[3] = (bf16_t)(fminf(fmaxf(rintf(v.w * inv), -8.f), 7.f) * s);
        reinterpret_cast<bf16x4*>(wq)[idx] = o;
    }
}

// ---------------- K4: fused GEMM (h + gate tiles) + LoRA + GEGLU ------------------
// EXACT round-3 structure (712 us, 0 bank conflicts, 46% occupancy).
// 512 thr = 8 waves. Waves 0-3: H tile (2x2 of 64x64); waves 4-7: G tile.
// Both-sides XOR swizzle: global source chunk col ^= row&7; ds_read col16 ^= row&7.
__global__ __launch_bounds__(512, 2) void k_gemm(const bf16_t* __restrict__ xq,
                                                 const bf16_t* __restrict__ wq,
                                                 const bf16_t* __restrict__ T,
                                                 const bf16_t* __restrict__ lub,
                                                 float* __restrict__ out) {
    __shared__ __align__(16) char smem[65536];       // staging 48KB; epilogue exch 64KB
    bf16_t* sA = (bf16_t*)smem;                      // [128][64]
    bf16_t* sH = sA + BM * BK;
    bf16_t* sG = sH + BN * BK;

    int tid = threadIdx.x, lane = tid & 63, w = tid >> 6;
    int half = w >> 2;                 // 0 = H, 1 = G
    int wr = (w & 3) >> 1, wc = w & 1;

    // XCD-bijective swizzle (3072 % 8 == 0)
    int nwg = gridDim.x;
    int cpx = nwg >> 3;
    int swz = (blockIdx.x & 7) * cpx + (blockIdx.x >> 3);
    int mt = swz & 31, nt = swz >> 5;  // mt fast: neighbors share B tiles
    int m0 = mt * BM, c0 = nt * BN;

    f32x4 acc[4][4];
#pragma unroll
    for (int i = 0; i < 4; ++i)
#pragma unroll
        for (int j = 0; j < 4; ++j) acc[i][j] = (f32x4){0.f, 0.f, 0.f, 0.f};

    const char* sBb = (const char*)(half ? sG : sH);
    const char* sAb = (const char*)sA;

    for (int k0 = 0; k0 < DIN; k0 += BK) {
        __syncthreads();
        // stage 3 tiles of 128x64 bf16; 1024 16B-chunks each; 512 lanes -> 2 rounds.
#pragma unroll
        for (int r = 0; r < 2; ++r) {
            int chunk = r * 512 + tid;
            int row = chunk >> 3;
            int gc = ((chunk & 7) ^ (row & 7)) * 8;
            int ldsoff = r * 4096 + w * 512;
            GLD16(xq + (size_t)(m0 + row) * DIN + k0 + gc, sA + ldsoff);
            GLD16(wq + (size_t)(c0 + row) * DIN + k0 + gc, sH + ldsoff);
            GLD16(wq + (size_t)(c0 + HALF + row) * DIN + k0 + gc, sG + ldsoff);
        }
        __syncthreads();   // vmcnt(0) drain before barrier

#pragma unroll
        for (int ks = 0; ks < 2; ++ks) {
            int c16 = ks * 4 + (lane >> 4);
            bf16x8 a[4], b[4];
#pragma unroll
            for (int i = 0; i < 4; ++i) {
                int ra = wr * 64 + i * 16 + (lane & 15);
                int rb = wc * 64 + i * 16 + (lane & 15);
                a[i] = *reinterpret_cast<const bf16x8*>(sAb + ra * 128 + ((c16 ^ (ra & 7)) << 4));
                b[i] = *reinterpret_cast<const bf16x8*>(sBb + rb * 128 + ((c16 ^ (rb & 7)) << 4));
            }
#pragma unroll
            for (int m = 0; m < 4; ++m)
#pragma unroll
                for (int n = 0; n < 4; ++n)
                    acc[m][n] = __builtin_amdgcn_mfma_f32_16x16x32_bf16(a[m], b[n], acc[m][n], 0, 0, 0);
        }
    }

    // ---- LoRA correction: one K=32 MFMA per fragment (RANK == 32) ----
    {
        bf16x8 tf[4];
#pragma unroll
        for (int m = 0; m < 4; ++m)
            tf[m] = *reinterpret_cast<const bf16x8*>(
                T + (size_t)(m0 + wr * 64 + m * 16 + (lane & 15)) * 32 + (lane >> 4) * 8);
#pragma unroll
        for (int n = 0; n < 4; ++n) {
            bf16x8 lu = *reinterpret_cast<const bf16x8*>(
                lub + (size_t)(c0 + half * HALF + wc * 64 + n * 16 + (lane & 15)) * 32 + (lane >> 4) * 8);
#pragma unroll
            for (int m = 0; m < 4; ++m)
                acc[m][n] = __builtin_amdgcn_mfma_f32_16x16x32_bf16(tf[m], lu, acc[m][n], 0, 0, 0);
        }
    }

    // ---- GEGLU epilogue via LDS exchange: G waves write gelu(g); H waves combine --
    __syncthreads();                    // all LDS staging reads done; reuse smem
    float* exch = (float*)smem;         // [128][128] f32, col XOR-swizzled
    if (half) {
#pragma unroll
        for (int m = 0; m < 4; ++m)
#pragma unroll
            for (int n = 0; n < 4; ++n) {
                int col = wc * 64 + n * 16 + (lane & 15);
#pragma unroll
                for (int r = 0; r < 4; ++r) {
                    int row = wr * 64 + m * 16 + (lane >> 4) * 4 + r;
                    float g = acc[m][n][r];
                    float gl = 0.5f * g * (1.0f + erff(g * 0.70710678118654752f));
                    exch[row * 128 + (col ^ (((row >> 2) & 3) << 4))] = gl;
                }
            }
    }
    __syncthreads();
    if (!half) {
#pragma unroll
        for (int m = 0; m < 4; ++m)
#pragma unroll
            for (int n = 0; n < 4; ++n) {
                int col = wc * 64 + n * 16 + (lane & 15);
#pragma unroll
                for (int r = 0; r < 4; ++r) {
                    int row = wr * 64 + m * 16 + (lane >> 4) * 4 + r;
                    float gl = exch[row * 128 + (col ^ (((row >> 2) & 3) << 4))];
                    out[(size_t)(m0 + row) * HALF + c0 + col] = acc[m][n][r] * gl;
                }
            }
    }
}

extern "C" void kernel_launch(void* const* d_in, const int* in_sizes, int n_in,
                              void* d_out, int out_size, void* d_ws, size_t ws_size,
                              hipStream_t stream) {
    const float* x  = (const float*)d_in[0];   // [1,4096,3072]
    const float* wr = (const float*)d_in[1];   // [24576,3072]
    const float* ld = (const float*)d_in[2];   // [32,3072]
    const float* lu = (const float*)d_in[3];   // [24576,32]
    float* out = (float*)d_out;                // [4096,12288] f32

    bf16_t* xq  = (bf16_t*)d_ws;
    bf16_t* wq  = xq + (size_t)MTOK * DIN;
    bf16_t* T   = wq + (size_t)NOUT * DIN;
    bf16_t* lub = T  + (size_t)MTOK * 32;

    k_prep<<<NB_PREP, 256, 0, stream>>>(x, wr, ld, lu, xq, wq, T, lub);
    k_gemm<<<(MTOK / BM) * (HALF / BN), 512, 0, stream>>>(xq, wq, T, lub, out);
}